// Round 4
// baseline (710.334 us; speedup 1.0000x reference)
//
#include <hip/hip_runtime.h>
#include <stdint.h>
#include <math.h>

// MoE FFN: x[4096,1024], top-2 of 8 experts, W1[E,1024,4096], W2[E,4096,1024]
// Sparse bf16-MFMA, 256^2 double-buffered ring GEMM w/ counted vmcnt.
// Compact-h layout keeps workspace at ~210 MB (< proven 218 MB capacity).

#define D_MODEL 1024
#define D_FF    4096
#define NEXP    8
#define MAXN    4096
#define BM 256
#define BN 256
#define BK 64
#define MAXROWS (2*MAXN + NEXP*BM)   // padded row-space upper bound (off_pad values)
#define NTM (MAXROWS/BM)             // 40 row tiles
#define HROWS (2*MAXN + 8)           // compact h rows + dump rows
#define HDUMP (2*MAXN)               // dump row index for padding writes

typedef __attribute__((ext_vector_type(8))) short bf16x8;  // 8 bf16 = 4 VGPRs
typedef __attribute__((ext_vector_type(4))) float f32x4;

__device__ __forceinline__ unsigned short f2bf(float f) {
  union { float f; uint32_t u; } v; v.f = f;
  uint32_t u = v.u;
  uint32_t r = (u + 0x7FFFu + ((u >> 16) & 1u)) >> 16;  // RNE
  return (unsigned short)r;
}

#define GLOAD_LDS16(src, dst) \
  __builtin_amdgcn_global_load_lds((const __attribute__((address_space(1))) void*)(src), \
                                   (__attribute__((address_space(3))) void*)(dst), 16, 0, 0)

// ---------------- gate: fp32 logits -> softmax -> top2 -> per-expert lists ----------------
__global__ __launch_bounds__(256) void gate_kernel(
    const float* __restrict__ x, const float* __restrict__ gw, int N,
    int* __restrict__ counts, int* __restrict__ toklist, float* __restrict__ wlist) {
  int lane = threadIdx.x & 63;
  int wid  = threadIdx.x >> 6;
  int n = blockIdx.x * 4 + wid;
  if (n >= N) return;
  const float* xr = x + (size_t)n * D_MODEL;
  float p[NEXP];
#pragma unroll
  for (int e = 0; e < NEXP; ++e) p[e] = 0.f;
  for (int i = lane; i < D_MODEL; i += 64) {
    float xv = xr[i];
#pragma unroll
    for (int e = 0; e < NEXP; ++e) p[e] += xv * gw[e * D_MODEL + i];
  }
#pragma unroll
  for (int e = 0; e < NEXP; ++e) {
#pragma unroll
    for (int off = 32; off > 0; off >>= 1) p[e] += __shfl_xor(p[e], off);
  }
  if (lane == 0) {
    float m = p[0];
#pragma unroll
    for (int e = 1; e < NEXP; ++e) m = fmaxf(m, p[e]);
    float sc[NEXP]; float s = 0.f;
#pragma unroll
    for (int e = 0; e < NEXP; ++e) { sc[e] = expf(p[e] - m); s += sc[e]; }
    float inv = 1.f / s;
    int i0 = 0; float b0 = sc[0];
#pragma unroll
    for (int e = 1; e < NEXP; ++e) if (sc[e] > b0) { b0 = sc[e]; i0 = e; }
    int i1 = -1; float b1 = -1.f;
#pragma unroll
    for (int e = 0; e < NEXP; ++e) if (e != i0 && sc[e] > b1) { b1 = sc[e]; i1 = e; }
    int p0 = atomicAdd(&counts[i0], 1);
    toklist[i0 * MAXN + p0] = n; wlist[i0 * MAXN + p0] = b0 * inv;
    int p1 = atomicAdd(&counts[i1], 1);
    toklist[i1 * MAXN + p1] = n; wlist[i1 * MAXN + p1] = b1 * inv;
  }
}

// ---------------- offsets: padded (BM) and compact cumulative ----------------
__global__ void offsets_kernel(const int* __restrict__ counts,
                               int* __restrict__ off_pad, int* __restrict__ cum) {
  if (threadIdx.x == 0 && blockIdx.x == 0) {
    int o = 0, c = 0; off_pad[0] = 0; cum[0] = 0;
    for (int e = 0; e < NEXP; ++e) {
      o += (counts[e] + BM - 1) & ~(BM - 1); off_pad[e + 1] = o;
      c += counts[e];                        cum[e + 1] = c;
    }
  }
}

__global__ __launch_bounds__(128) void fill_rows(
    const int* __restrict__ counts, const int* __restrict__ off_pad,
    const int* __restrict__ cum,
    const int* __restrict__ toklist, const float* __restrict__ wlist,
    int* __restrict__ row_token, float* __restrict__ row_weight,
    int* __restrict__ row_compact) {
  int e = blockIdx.x; int pos = blockIdx.y * 128 + threadIdx.x;
  int base = off_pad[e]; int span = off_pad[e + 1] - base;
  if (pos >= span) return;
  int cnt = counts[e];
  if (pos < cnt) {
    row_token[base + pos]   = toklist[e * MAXN + pos];
    row_weight[base + pos]  = wlist[e * MAXN + pos];
    row_compact[base + pos] = cum[e] + pos;
  } else {
    row_token[base + pos]   = 0;
    row_weight[base + pos]  = 0.f;
    row_compact[base + pos] = HDUMP;   // padding rows write/read a dump row
  }
}

// ---------------- fp32 -> bf16 convert (linear) ----------------
__global__ __launch_bounds__(256) void cvt_x(const float* __restrict__ in,
                                             unsigned short* __restrict__ out, int n4) {
  int i = blockIdx.x * 256 + threadIdx.x;
  if (i >= n4) return;
  float4 v = ((const float4*)in)[i];
  ushort4 o; o.x = f2bf(v.x); o.y = f2bf(v.y); o.z = f2bf(v.z); o.w = f2bf(v.w);
  ((ushort4*)out)[i] = o;
}

// ---------------- fp32 [R][C] -> bf16 [C][R] transpose-convert, per expert z ----------------
__global__ __launch_bounds__(256) void transpose_cvt(const float* __restrict__ in,
                                                     unsigned short* __restrict__ out,
                                                     int R, int C) {
  __shared__ float tile[64][65];
  size_t es = (size_t)R * C;
  in  += (size_t)blockIdx.z * es;
  out += (size_t)blockIdx.z * es;
  int c0 = blockIdx.x * 64, r0 = blockIdx.y * 64;
  int t = threadIdx.x;
  int rl = t >> 4, cq = (t & 15) * 4;
#pragma unroll
  for (int p = 0; p < 4; ++p) {
    int row = p * 16 + rl;
    float4 v = *(const float4*)(in + (size_t)(r0 + row) * C + c0 + cq);
    tile[row][cq] = v.x; tile[row][cq + 1] = v.y; tile[row][cq + 2] = v.z; tile[row][cq + 3] = v.w;
  }
  __syncthreads();
#pragma unroll
  for (int p = 0; p < 4; ++p) {
    int cl = p * 16 + rl;
    ushort4 o;
    o.x = f2bf(tile[cq][cl]); o.y = f2bf(tile[cq + 1][cl]);
    o.z = f2bf(tile[cq + 2][cl]); o.w = f2bf(tile[cq + 3][cl]);
    *(ushort4*)(out + (size_t)(c0 + cl) * R + r0 + cq) = o;
  }
}

// ---------------- 256x256 ring-pipelined MFMA GEMM ----------------
// C[rows, Ncols] = A_gathered[rows,K] * B_e^T  (B stored [E][Ncols][K] bf16, K-contiguous)
// A rows gathered via rowlist (gemm1: row_token -> xb; gemm2: row_compact -> h).
// EPI 1: h[row_compact] = bf16(gelu(acc)).  EPI 2: atomicAdd(out[row_token], acc*w).
// 512 thr = 8 waves (2M x 4N); per-wave 128x64 out; BK=64; LDS 2 x (A 32K + B 32K) = 128 KiB.
// Ring: stage tile kt+1 at top of tile kt; s_waitcnt vmcnt(8) (counted, never 0 mid-loop);
// raw s_barrier (no compiler vmcnt(0) drain). Swizzle: LDS chunk c holds k-chunk c^(row&7),
// realized via pre-swizzled global source (both-sides rule).
template<int EPI, int NTN>
__global__ __launch_bounds__(512, 2) void gemm_moe(
    const unsigned short* __restrict__ A, const unsigned short* __restrict__ B,
    int K, int nwg, const int* __restrict__ off_pad,
    const int* __restrict__ rowlist,
    const int* __restrict__ row_token, const float* __restrict__ row_weight,
    const int* __restrict__ row_compact,
    unsigned short* __restrict__ hout, float* __restrict__ out) {
  __shared__ alignas(16) char lds[2][65536];  // [buf][A:0..32767 | B:32768..65535]

  // bijective XCD swizzle (m204): contiguous ids (same m-tile) land on one XCD
  int orig = blockIdx.x;
  int q = nwg >> 3, r = nwg & 7;
  int xcd = orig & 7, within = orig >> 3;
  int id = (xcd < r ? xcd * (q + 1) : r * (q + 1) + (xcd - r) * q) + within;
  int mt = id / NTN, nt = id % NTN;
  int row0 = mt * BM;
  if (row0 >= off_pad[NEXP]) return;   // uniform early-exit, before any barrier
  int e = 0;
#pragma unroll
  for (int t = 1; t < NEXP; ++t) if (row0 >= off_pad[t]) e = t;
  int n0 = nt * BN;
  int tid = threadIdx.x, lane = tid & 63, w = tid >> 6;
  int wm = w >> 2, wn = w & 3;

  // ---- staging addresses: 8 gload_lds(16B)/thread/tile (4 A + 4 B) ----
  int srow = lane >> 3;                       // row within 8-row group == row&7
  int swz = ((lane & 7) ^ srow) << 4;         // pre-swizzled source chunk
  const char* aSrc[4]; const char* bSrc[4];
  int ldsA[4], ldsB[4];
#pragma unroll
  for (int i = 0; i < 4; ++i) {
    int rowi = w * 32 + i * 8 + srow;         // 0..255
    size_t ar = (size_t)rowlist[row0 + rowi];
    aSrc[i] = (const char*)(A + ar * (size_t)K) + swz;
    bSrc[i] = (const char*)(B + ((size_t)e * (NTN * BN) + (size_t)(n0 + rowi)) * (size_t)K) + swz;
    ldsA[i] = (w * 32 + i * 8) * 128;         // wave-uniform LDS dest
    ldsB[i] = 32768 + (w * 32 + i * 8) * 128;
  }

  f32x4 acc[8][4];
  f32x4 zero = {0.f, 0.f, 0.f, 0.f};
#pragma unroll
  for (int m = 0; m < 8; ++m)
#pragma unroll
    for (int n = 0; n < 4; ++n) acc[m][n] = zero;

  int rA = lane & 15, hi = lane >> 4;
  int nkt = K / BK;

#define STAGE(kt, buf) do {                                                  \
    size_t koff_ = (size_t)(kt) * 128;                                       \
    _Pragma("unroll")                                                        \
    for (int i_ = 0; i_ < 4; ++i_) {                                         \
      GLOAD_LDS16(aSrc[i_] + koff_, (char*)lds[buf] + ldsA[i_]);             \
      GLOAD_LDS16(bSrc[i_] + koff_, (char*)lds[buf] + ldsB[i_]);             \
    }                                                                        \
  } while (0)

  STAGE(0, 0);  // prologue

  for (int kt = 0; kt < nkt; ++kt) {
    int cur = kt & 1;
    if (kt + 1 < nkt) {
      STAGE(kt + 1, cur ^ 1);
      asm volatile("s_waitcnt vmcnt(8)" ::: "memory");   // tile kt landed; kt+1 stays in flight
    } else {
      asm volatile("s_waitcnt vmcnt(0)" ::: "memory");   // tail drain
    }
    __builtin_amdgcn_sched_barrier(0);
    __builtin_amdgcn_s_barrier();                        // cross-wave: buf[cur] complete

    const char* Ab = (const char*)lds[cur];
    const char* Bb = (const char*)lds[cur] + 32768;
#pragma unroll
    for (int kk = 0; kk < 2; ++kk) {
      bf16x8 af[8], bfr[4];
#pragma unroll
      for (int m = 0; m < 8; ++m) {
        int row = wm * 128 + m * 16 + rA;
        af[m] = *(const bf16x8*)(Ab + row * 128 + (((kk * 4 + hi) ^ (rA & 7)) << 4));
      }
#pragma unroll
      for (int n = 0; n < 4; ++n) {
        int row = wn * 64 + n * 16 + rA;
        bfr[n] = *(const bf16x8*)(Bb + row * 128 + (((kk * 4 + hi) ^ (rA & 7)) << 4));
      }
      asm volatile("s_waitcnt lgkmcnt(0)" ::: "memory");
      __builtin_amdgcn_sched_barrier(0);
      __builtin_amdgcn_s_setprio(1);
#pragma unroll
      for (int m = 0; m < 8; ++m)
#pragma unroll
        for (int n = 0; n < 4; ++n)
          acc[m][n] = __builtin_amdgcn_mfma_f32_16x16x32_bf16(af[m], bfr[n], acc[m][n], 0, 0, 0);
      __builtin_amdgcn_s_setprio(0);
    }
    __builtin_amdgcn_s_barrier();   // all reads of buf[cur] done -> next tile may overwrite
  }
#undef STAGE

  if (EPI == 1) {
#pragma unroll
    for (int m = 0; m < 8; ++m) {
      int rbase = row0 + wm * 128 + m * 16 + hi * 4;
      int4 cv = *(const int4*)(row_compact + rbase);   // compact h row indices
#pragma unroll
      for (int j = 0; j < 4; ++j) {
        int cr = j == 0 ? cv.x : j == 1 ? cv.y : j == 2 ? cv.z : cv.w;
        size_t rb = (size_t)cr * D_FF + n0 + wn * 64 + rA;
#pragma unroll
        for (int n = 0; n < 4; ++n) {
          float v = acc[m][n][j];
          v = 0.5f * v * (1.f + erff(v * 0.70710678118654752f));
          hout[rb + n * 16] = f2bf(v);
        }
      }
    }
  } else {
#pragma unroll
    for (int m = 0; m < 8; ++m) {
      int rbase = row0 + wm * 128 + m * 16 + hi * 4;
      float4 wv = *(const float4*)(row_weight + rbase);
      int4   tv = *(const int4*)(row_token + rbase);
#pragma unroll
      for (int j = 0; j < 4; ++j) {
        float wgt = j == 0 ? wv.x : j == 1 ? wv.y : j == 2 ? wv.z : wv.w;
        int   tok = j == 0 ? tv.x : j == 1 ? tv.y : j == 2 ? tv.z : tv.w;
        if (wgt != 0.f) {
          float* orow = out + (size_t)tok * D_MODEL + n0 + wn * 64 + rA;
#pragma unroll
          for (int n = 0; n < 4; ++n)
            atomicAdd(orow + n * 16, acc[m][n][j] * wgt);
        }
      }
    }
  }
}

extern "C" void kernel_launch(void* const* d_in, const int* in_sizes, int n_in,
                              void* d_out, int out_size, void* d_ws, size_t ws_size,
                              hipStream_t stream) {
  const float* x  = (const float*)d_in[0];
  const float* gw = (const float*)d_in[1];
  const float* W1 = (const float*)d_in[2];
  const float* W2 = (const float*)d_in[3];
  float* out = (float*)d_out;
  int N = in_sizes[0] / D_MODEL;  // 4096

  char* ws = (char*)d_ws;
  size_t o = 0;
  auto alloc = [&](size_t b) { size_t r = o; o += (b + 255) & ~255ULL; return r; };
  int*            counts     = (int*)(ws + alloc(NEXP * 4));
  int*            off_pad    = (int*)(ws + alloc((NEXP + 1) * 4));
  int*            cum        = (int*)(ws + alloc((NEXP + 1) * 4));
  int*            toklist    = (int*)(ws + alloc((size_t)NEXP * MAXN * 4));
  float*          wlist      = (float*)(ws + alloc((size_t)NEXP * MAXN * 4));
  int*            row_token  = (int*)(ws + alloc(MAXROWS * 4));
  float*          row_weight = (float*)(ws + alloc(MAXROWS * 4));
  int*            row_compact= (int*)(ws + alloc(MAXROWS * 4));
  unsigned short* xb         = (unsigned short*)(ws + alloc((size_t)N * D_MODEL * 2));
  unsigned short* w1t        = (unsigned short*)(ws + alloc((size_t)NEXP * D_MODEL * D_FF * 2));
  unsigned short* w2t        = (unsigned short*)(ws + alloc((size_t)NEXP * D_MODEL * D_FF * 2));
  unsigned short* h          = (unsigned short*)(ws + alloc((size_t)HROWS * D_FF * 2));
  (void)ws_size; (void)n_in;  // total ~210.2 MB (< 218.3 MB proven capacity)

  hipMemsetAsync(counts, 0, NEXP * sizeof(int), stream);
  hipMemsetAsync(d_out, 0, (size_t)out_size * sizeof(float), stream);

  gate_kernel<<<N / 4, 256, 0, stream>>>(x, gw, N, counts, toklist, wlist);
  offsets_kernel<<<1, 1, 0, stream>>>(counts, off_pad, cum);
  fill_rows<<<dim3(NEXP, MAXN / 128), 128, 0, stream>>>(
      counts, off_pad, cum, toklist, wlist, row_token, row_weight, row_compact);
  cvt_x<<<(N * D_MODEL / 4 + 255) / 256, 256, 0, stream>>>(x, xb, N * D_MODEL / 4);
  transpose_cvt<<<dim3(D_FF / 64, D_MODEL / 64, NEXP), 256, 0, stream>>>(W1, w1t, D_MODEL, D_FF);
  transpose_cvt<<<dim3(D_MODEL / 64, D_FF / 64, NEXP), 256, 0, stream>>>(W2, w2t, D_FF, D_MODEL);

  // gemm1: gather xb rows -> [rows,1024] x W1_e -> h[compact rows, 4096], GELU
  gemm_moe<1, D_FF / BN><<<NTM * (D_FF / BN), 512, 0, stream>>>(
      xb, w1t, D_MODEL, NTM * (D_FF / BN), off_pad,
      row_token, row_token, row_weight, row_compact, h, nullptr);
  // gemm2: gather h rows -> [rows,4096] x W2_e -> scatter into out[token,1024]
  gemm_moe<2, D_MODEL / BN><<<NTM * (D_MODEL / BN), 512, 0, stream>>>(
      h, w2t, D_FF, NTM * (D_MODEL / BN), off_pad,
      row_compact, row_token, row_weight, row_compact, nullptr, out);
}